// Round 8
// baseline (236.144 us; speedup 1.0000x reference)
//
#include <hip/hip_runtime.h>
#include <math.h>

#define NC 19
#define NB 8
#define HW (512 * 512)
#define CHUNKS 32
#define NG 5       // channel quads {0-3},{4-7},{8-11},{12-15},{16,17,18,+count}
#define TPB 256
#define FT 1024

typedef float v4f __attribute__((ext_vector_type(4)));
typedef int v4i __attribute__((ext_vector_type(4)));

// Workspace: S_part[NB][CHUNKS][NC][20] floats (389,120 B). Unique slot per
// (b,chunk,t,col): col c in 0..18 = sum of channel c over class-t pixels,
// col 19 = class-t count. Every slot written unconditionally -> no memset.

__global__ __launch_bounds__(TPB) void accum_kernel(const float* __restrict__ seg,
                                                    const int* __restrict__ tgt,
                                                    float* __restrict__ S_part) {
    // Per-thread PRIVATE float4 bins: ONE ds_read_b128 + packed add + ONE
    // ds_write_b128 per pixel covers 4 channels (R7 was LDS-instr-bound at
    // 16 b32 ops/pixel-quad; this is 8 b128 ops -> ~4x fewer LDS cycles).
    // Stride 19 float4/thread: bank-quad = (3*tid) mod 8 covers all 8 quads.
    // 304 B/thread -> 76 KB/block -> 2 blocks/CU.
    __shared__ __align__(16) v4f bins[TPB * NC];

    const int tid = threadIdx.x;
    const int g = blockIdx.x;      // FASTEST: 5 groups sharing one target chunk
    const int chunk = blockIdx.y;  //   are co-dispatched -> target L2/L3 hits
    const int b = blockIdx.z;
    const bool last = (g == NG - 1);
    const int c0 = 4 * g;

    v4f* __restrict__ mybins = &bins[tid * NC];
    #pragma unroll
    for (int k = 0; k < NC; ++k) mybins[k] = (v4f){0.f, 0.f, 0.f, 0.f};
    // Rows are thread-private until the fold: no barrier needed here.

    const int per_chunk = HW / CHUNKS;  // 8192 pixels
    const size_t pix = (size_t)chunk * per_chunk;
    const float* segb = seg + (size_t)b * NC * HW + pix;
    const v4f* __restrict__ s0 = (const v4f*)(segb + (size_t)(c0 + 0) * HW);
    const v4f* __restrict__ s1 = (const v4f*)(segb + (size_t)(c0 + 1) * HW);
    const v4f* __restrict__ s2 = (const v4f*)(segb + (size_t)(c0 + 2) * HW);
    const v4f* __restrict__ s3 = (const v4f*)(segb + (size_t)(last ? c0 + 2 : c0 + 3) * HW);
    const v4i* __restrict__ tv = (const v4i*)(tgt + (size_t)b * HW + pix);

    const int iters = per_chunk / 4 / TPB;  // 8
    const v4f ones = {1.0f, 1.0f, 1.0f, 1.0f};

    // Depth-1 software pipeline (plain cacheable loads: seg/tgt are L3-warm
    // after the harness restore; nt would forfeit that).
    int v = tid;
    v4i t = tv[v];
    v4f z0 = s0[v], z1 = s1[v], z2 = s2[v];
    v4f z3 = last ? ones : s3[v];

    for (int i = 0; i < iters; ++i) {
        v4i tn = {};
        v4f n0 = {}, n1 = {}, n2 = {}, n3 = ones;
        if (i + 1 < iters) {
            const int vn = v + TPB;
            tn = tv[vn];
            n0 = s0[vn]; n1 = s1[vn]; n2 = s2[vn];
            if (!last) n3 = s3[vn];
        }
        // 4 dependent b128 RMWs (possible aliasing among t.x..t.w); each one
        // updates 4 channels at once. Bin component = channel; z*.comp = pixel.
        v4f c;
        c = mybins[t.x]; c.x += z0.x; c.y += z1.x; c.z += z2.x; c.w += z3.x; mybins[t.x] = c;
        c = mybins[t.y]; c.x += z0.y; c.y += z1.y; c.z += z2.y; c.w += z3.y; mybins[t.y] = c;
        c = mybins[t.z]; c.x += z0.z; c.y += z1.z; c.z += z2.z; c.w += z3.z; mybins[t.z] = c;
        c = mybins[t.w]; c.x += z0.w; c.y += z1.w; c.z += z2.w; c.w += z3.w; mybins[t.w] = c;
        t = tn; z0 = n0; z1 = n1; z2 = n2; z3 = n3; v += TPB;
    }
    __syncthreads();

    // Stage 1: fold 256 rows -> 32 rows in the float4 domain, in-place safe.
    for (int e = tid; e < 32 * NC; e += TPB) {  // 608 float4 elements
        const int r = e & 31, c = e >> 5;  // c in 0..18
        v4f acc = bins[r * NC + c];
        #pragma unroll
        for (int j = 1; j < TPB / 32; ++j) acc += bins[(r + 32 * j) * NC + c];
        bins[r * NC + c] = acc;
    }
    __syncthreads();

    // Stage 2: 19 lanes (wave 0) sum the 32 rows of their class; store the 4
    // channel columns to this block's unique slots. Last group: cols 16,17,18
    // and 19 (count) -- contiguous, so all 20 cols are covered across g=0..4.
    if (tid < NC) {
        v4f acc = bins[tid];
        #pragma unroll
        for (int r = 1; r < 32; ++r) acc += bins[r * NC + tid];
        float* dst = S_part + (((size_t)(b * CHUNKS + chunk)) * NC + tid) * 20 + c0;
        dst[0] = acc.x; dst[1] = acc.y; dst[2] = acc.z; dst[3] = acc.w;
    }
}

__global__ __launch_bounds__(FT) void finalize_kernel(const float* __restrict__ S_part,
                                                      float* __restrict__ out) {
    __shared__ float S[NB * NC * 20];  // 3040 floats: S[b][t][c], col 19 = count
    __shared__ float wsum[FT / 64];
    const int tid = threadIdx.x;

    // Phase A: reduce the 32 chunk partials (coalesced: r contiguous).
    for (int e = tid; e < NB * NC * 20; e += FT) {
        const int b = e / (NC * 20);
        const int r = e - b * (NC * 20);
        float a = 0.0f;
        #pragma unroll
        for (int ch = 0; ch < CHUNKS; ++ch)
            a += S_part[((size_t)(b * CHUNKS + ch)) * (NC * 20) + r];
        S[e] = a;
    }
    __syncthreads();

    // Phase B: 2888 log terms.
    const float eps = 2.220446049250313e-16f;  // np.spacing(1)
    float local = 0.0f;
    for (int idx = tid; idx < NB * NC * NC; idx += FT) {
        const int b = idx / (NC * NC);
        const int r = idx - b * NC * NC;
        const int i = r / NC;
        const int k = r - i * NC;
        const float* Sb = S + b * NC * 20;  // Sb[t*20+c] = sum ch c over class t
        const float cnt_i = Sb[i * 20 + 19];
        const float cnt_k = Sb[k * 20 + 19];
        const float alpha = (cnt_i > 0.0f) ? Sb[i * 20 + i] / cnt_i : 0.0f;
        const float beta = (cnt_k > 0.0f) ? 1.0f - Sb[k * 20 + i] / cnt_k : 0.0f;
        local += logf(0.5f * (alpha + beta + eps));
    }

    #pragma unroll
    for (int off = 32; off > 0; off >>= 1) local += __shfl_down(local, off);
    if ((tid & 63) == 0) wsum[tid >> 6] = local;
    __syncthreads();
    if (tid == 0) {
        float t = 0.0f;
        #pragma unroll
        for (int w = 0; w < FT / 64; ++w) t += wsum[w];
        out[0] = -0.5f * t / (float)NB;
    }
}

extern "C" void kernel_launch(void* const* d_in, const int* in_sizes, int n_in,
                              void* d_out, int out_size, void* d_ws, size_t ws_size,
                              hipStream_t stream) {
    const float* seg = (const float*)d_in[0];
    const int* tgt = (const int*)d_in[1];
    float* S_part = (float*)d_ws;  // 389,120 B; every slot written unconditionally

    dim3 grid(NG, CHUNKS, NB);  // 5 x 32 x 8 = 1280 blocks, g fastest
    accum_kernel<<<grid, TPB, 0, stream>>>(seg, tgt, S_part);
    finalize_kernel<<<1, FT, 0, stream>>>(S_part, (float*)d_out);
}